// Round 2
// baseline (2182.520 us; speedup 1.0000x reference)
//
#include <hip/hip_runtime.h>
#include <hip/hip_bf16.h>

typedef unsigned short u16;
typedef __attribute__((ext_vector_type(8))) short   short8;
typedef __attribute__((ext_vector_type(8))) __bf16  bf16x8;
typedef __attribute__((ext_vector_type(16))) float  floatx16;

#define DD  128   // D
#define FE  16    // edge feature dim
#define DIN 145   // D + Fe + 1
#define K1  160   // Din padded to multiple of 16
#define K1P 168   // xs LDS row stride (shorts): 336 B (16B-aligned rows, 4-way max conflict)
#define HQ  256   // hidden width
#define HQP 264   // h1 LDS row stride (shorts); also f32 stride for the reduce view
#define ME  64    // edges per block   (E = 1,000,000 is divisible by 64)
#define MV  32    // variables per block (V = 200,000 is divisible by 32)

__device__ __forceinline__ float logsig(float x) {
    return fminf(x, 0.f) - __logf(1.f + __expf(-fabsf(x)));
}
// f32 -> bf16 RNE (bit trick; inputs are finite)
__device__ __forceinline__ u16 f2b(float f) {
    union { float f; unsigned u; } x; x.f = f;
    unsigned r = x.u + 0x7fffu + ((x.u >> 16) & 1u);
    return (u16)(r >> 16);
}
__device__ __forceinline__ ushort4 f2b4(float4 v) {
    ushort4 o; o.x = f2b(v.x); o.y = f2b(v.y); o.z = f2b(v.z); o.w = f2b(v.w);
    return o;
}
__device__ __forceinline__ bf16x8 ld_bf8_lds(const short* p) {
    return __builtin_bit_cast(bf16x8, *(const short8*)p);
}
__device__ __forceinline__ bf16x8 ld_bf8_glb(const short* p) {
    return __builtin_bit_cast(bf16x8, *(const short8*)p);
}

// ---------------------------------------------------------------------------
// Weight pre-conversion: f32 -> bf16 copies in workspace (re-done every call;
// d_ws is re-poisoned before each launch). W1m rows padded 145 -> 160 (zeros).
// ---------------------------------------------------------------------------
__global__ __launch_bounds__(256) void conv_weights(
    const float* __restrict__ W1m, const float* __restrict__ W2m,
    const float* __restrict__ W1a, const float* __restrict__ W2a,
    short* __restrict__ W1mb, short* __restrict__ W2mb,
    short* __restrict__ W1ab, short* __restrict__ W2ab)
{
    int i = blockIdx.x * 256 + threadIdx.x;
    if (i < 256 * K1) {                              // W1mb [256][160]
        int n = i / K1, k = i - n * K1;
        W1mb[i] = (k < DIN) ? (short)f2b(W1m[n * DIN + k]) : (short)0;
    } else if (i < 256 * K1 + 256 * HQ) {            // W2mb [256][256]
        int j = i - 256 * K1;
        W2mb[j] = (short)f2b(W2m[j]);
    } else if (i < 256 * K1 + 2 * 256 * HQ) {        // W1ab [256][256]
        int j = i - 256 * K1 - 256 * HQ;
        W1ab[j] = (short)f2b(W1a[j]);
    } else if (i < 256 * K1 + 2 * 256 * HQ + 128 * HQ) { // W2ab [128][256]
        int j = i - 256 * K1 - 2 * 256 * HQ;
        W2ab[j] = (short)f2b(W2a[j]);
    }
}

// ---------------------------------------------------------------------------
// Counting sort of edges by variable index: hist -> scan (1 block) -> scatter.
// Produces perm[E] (edge ids in variable-sorted order); sorted variable ids
// are recomputed on the fly as vidx[perm[p]] (saves a 4 MB svid array).
// Only launched when ws_size can hold the sort arrays.
// ---------------------------------------------------------------------------
__global__ __launch_bounds__(256) void hist_kernel(
    const int* __restrict__ vidx, int* __restrict__ cnt, int E)
{
    int e = blockIdx.x * 256 + threadIdx.x;
    if (e < E) atomicAdd(&cnt[vidx[e]], 1);
}

#define SCAN_T 1024
__global__ __launch_bounds__(SCAN_T) void scan_kernel(
    const int* __restrict__ cnt, int* __restrict__ cursor, int V)
{
    __shared__ int part[SCAN_T];
    const int tid = threadIdx.x;
    const int chunk = (V + SCAN_T - 1) / SCAN_T;   // 196 for V=200000
    int lo = tid * chunk, hi = lo + chunk;
    if (lo > V) lo = V;
    if (hi > V) hi = V;
    int s = 0;
    for (int i = lo; i < hi; ++i) s += cnt[i];
    part[tid] = s;
    __syncthreads();
    if (tid == 0) {                  // serial exclusive scan of 1024 partials (~µs)
        int run = 0;
        for (int i = 0; i < SCAN_T; ++i) { int t = part[i]; part[i] = run; run += t; }
    }
    __syncthreads();
    int p = part[tid];
    for (int i = lo; i < hi; ++i) { int t = cnt[i]; cursor[i] = p; p += t; }
}

__global__ __launch_bounds__(256) void scatter_kernel(
    const int* __restrict__ vidx, int* __restrict__ cursor,
    int* __restrict__ perm, int E)
{
    int e = blockIdx.x * 256 + threadIdx.x;
    if (e < E) {
        int p = atomicAdd(&cursor[vidx[e]], 1);
        perm[p] = e;
    }
}

// ---------------------------------------------------------------------------
// Edge stage (MFMA): x = [vs|ef|sign*sol] -> ls(ls(x@W1m^T+b1m)@W2m^T) -> agg.
// SORTED=true : edges pre-sorted by variable; in-block segmented sum in LDS,
//               plain stores for interior variables, atomicAdd only for the
//               <=2 block-boundary variables (~8M atomics total).
// SORTED=false: fallback == previous verified kernel (256M scalar atomics),
//               used only if ws_size can't hold the sort arrays.
// Block = 256 thr = 4 waves; tile = 64 edges; wave w owns hidden cols w*64..+63.
// mfma_f32_32x32x16_bf16 D layout: col=lane&31, row=(reg&3)+8*(reg>>2)+4*(lane>>5).
// ---------------------------------------------------------------------------
template <bool SORTED>
__global__ __launch_bounds__(256) void edge_mfma(
    const float* __restrict__ vs, const float* __restrict__ ef,
    const float* __restrict__ sol, const float* __restrict__ b1m,
    const short* __restrict__ W1mb, const short* __restrict__ W2mb,
    const int* __restrict__ perm, const int* __restrict__ vidx,
    const int* __restrict__ esign, float* __restrict__ agg, int E)
{
    __shared__ short xs[ME][K1P];    // 21504 B
    __shared__ short h1s[ME][HQP];   // 33792 B (reused as float [32][HQP] in epilogue)
    __shared__ int   eid[ME];        //   256 B
    __shared__ int   svd[ME];        //   256 B
    __shared__ int   bflags;         // bit0: first var shared w/ prev block, bit1: last w/ next
    const int tid = threadIdx.x;
    const int e0 = blockIdx.x * ME;

    if (tid < ME) {
        int ge;
        if constexpr (SORTED) ge = perm[e0 + tid]; else ge = e0 + tid;
        eid[tid] = ge;
        svd[tid] = vidx[ge];
    }
    if constexpr (SORTED) {
        if (tid == 0) {
            int f = 0;
            if (e0 > 0      && vidx[perm[e0 - 1]]  == vidx[perm[e0]])          f |= 1;
            if (e0 + ME < E && vidx[perm[e0 + ME]] == vidx[perm[e0 + ME - 1]]) f |= 2;
            bflags = f;
        }
    }
    __syncthreads();

    // ---- gather: vs rows (64 x 128 f32, 512B/row) ----
    for (int i = tid; i < ME * 32; i += 256) {
        int e = i >> 5, q = (i & 31) << 2;
        float4 v = *(const float4*)&vs[(size_t)eid[e] * DD + q];
        *(ushort4*)&xs[e][q] = f2b4(v);
    }
    // ---- ef (64 x 16 f32) ----
    for (int i = tid; i < ME * 4; i += 256) {
        int e = i >> 2, q = (i & 3) << 2;
        float4 v = *(const float4*)&ef[(size_t)eid[e] * FE + q];
        *(ushort4*)&xs[e][DD + q] = f2b4(v);
    }
    // ---- signed solution column + K-pad ----
    for (int i = tid; i < ME * 16; i += 256) {
        int e = i >> 4, k = i & 15;
        if (k == 0) {
            int ge = eid[e];
            xs[e][144] = (short)f2b((float)esign[ge] * sol[svd[e]]);
        } else {
            xs[e][144 + k] = 0;
        }
    }
    __syncthreads();

    const int wv = tid >> 6, lane = tid & 63;
    const int lr = lane & 31, lh = lane >> 5;
    const int n0 = wv * 64;

    // ---- layer 1: [64 x 160] @ [160 x 64-chunk] ----
    floatx16 a00 = {}, a01 = {}, a10 = {}, a11 = {};
    #pragma unroll
    for (int ks = 0; ks < K1 / 16; ++ks) {
        int k = ks * 16 + lh * 8;
        bf16x8 A0 = ld_bf8_lds(&xs[lr][k]);
        bf16x8 A1 = ld_bf8_lds(&xs[32 + lr][k]);
        bf16x8 B0 = ld_bf8_glb(&W1mb[(size_t)(n0 + lr) * K1 + k]);
        bf16x8 B1 = ld_bf8_glb(&W1mb[(size_t)(n0 + 32 + lr) * K1 + k]);
        a00 = __builtin_amdgcn_mfma_f32_32x32x16_bf16(A0, B0, a00, 0, 0, 0);
        a01 = __builtin_amdgcn_mfma_f32_32x32x16_bf16(A0, B1, a01, 0, 0, 0);
        a10 = __builtin_amdgcn_mfma_f32_32x32x16_bf16(A1, B0, a10, 0, 0, 0);
        a11 = __builtin_amdgcn_mfma_f32_32x32x16_bf16(A1, B1, a11, 0, 0, 0);
    }
    {
        float bn0 = b1m[n0 + lr], bn1 = b1m[n0 + 32 + lr];
        #pragma unroll
        for (int r = 0; r < 16; ++r) {
            int row = (r & 3) + 8 * (r >> 2) + 4 * lh;
            h1s[row][n0 + lr]           = (short)f2b(logsig(a00[r] + bn0));
            h1s[row][n0 + 32 + lr]      = (short)f2b(logsig(a01[r] + bn1));
            h1s[32 + row][n0 + lr]      = (short)f2b(logsig(a10[r] + bn0));
            h1s[32 + row][n0 + 32 + lr] = (short)f2b(logsig(a11[r] + bn1));
        }
    }
    __syncthreads();

    // ---- layer 2: [64 x 256] @ [256 x 64-chunk] ----
    a00 = (floatx16){}; a01 = (floatx16){}; a10 = (floatx16){}; a11 = (floatx16){};
    #pragma unroll
    for (int ks = 0; ks < HQ / 16; ++ks) {
        int k = ks * 16 + lh * 8;
        bf16x8 A0 = ld_bf8_lds(&h1s[lr][k]);
        bf16x8 A1 = ld_bf8_lds(&h1s[32 + lr][k]);
        bf16x8 B0 = ld_bf8_glb(&W2mb[(size_t)(n0 + lr) * HQ + k]);
        bf16x8 B1 = ld_bf8_glb(&W2mb[(size_t)(n0 + 32 + lr) * HQ + k]);
        a00 = __builtin_amdgcn_mfma_f32_32x32x16_bf16(A0, B0, a00, 0, 0, 0);
        a01 = __builtin_amdgcn_mfma_f32_32x32x16_bf16(A0, B1, a01, 0, 0, 0);
        a10 = __builtin_amdgcn_mfma_f32_32x32x16_bf16(A1, B0, a10, 0, 0, 0);
        a11 = __builtin_amdgcn_mfma_f32_32x32x16_bf16(A1, B1, a11, 0, 0, 0);
    }

    if constexpr (SORTED) {
        // ---- epilogue: in-block segmented sum over sorted rows ----
        __syncthreads();                       // all waves done reading h1s (layer-2 A)
        float* h1f = (float*)&h1s[0][0];       // [32][HQP] f32 view (33792 B, exact fit)
        const int vF = svd[0], vL = svd[ME - 1];
        const int fl = bflags;

        auto flush = [&](int v, float a) {
            bool sh = (v == vF && (fl & 1)) || (v == vL && (fl & 2));
            float* dst = &agg[(size_t)v * HQ + tid];
            if (sh) atomicAdd(dst, a);         // boundary var: shared with neighbor block
            else    *dst = a;                  // interior var: this block owns the full sum
        };

        // pass A: logical rows 0..31 (a00/a01)
        #pragma unroll
        for (int r = 0; r < 16; ++r) {
            int row = (r & 3) + 8 * (r >> 2) + 4 * lh;
            h1f[row * HQP + n0 + lr]      = logsig(a00[r]);
            h1f[row * HQP + n0 + 32 + lr] = logsig(a01[r]);
        }
        __syncthreads();
        int cur = -1; float acc = 0.f;
        for (int r = 0; r < 32; ++r) {         // thread owns column tid; branch is uniform
            int v = svd[r]; float val = h1f[r * HQP + tid];
            if (v != cur) {
                if (cur >= 0) flush(cur, acc);
                cur = v; acc = val;
            } else acc += val;
        }
        __syncthreads();
        // pass B: logical rows 32..63 (a10/a11)
        #pragma unroll
        for (int r = 0; r < 16; ++r) {
            int row = (r & 3) + 8 * (r >> 2) + 4 * lh;
            h1f[row * HQP + n0 + lr]      = logsig(a10[r]);
            h1f[row * HQP + n0 + 32 + lr] = logsig(a11[r]);
        }
        __syncthreads();
        for (int r = 0; r < 32; ++r) {
            int v = svd[32 + r]; float val = h1f[r * HQP + tid];
            if (v != cur) {
                if (cur >= 0) flush(cur, acc);
                cur = v; acc = val;
            } else acc += val;
        }
        flush(cur, acc);                       // final run (cur >= 0 always)
    } else {
        // ---- fallback epilogue: logsig + coalesced f32 atomics (previous kernel) ----
        #pragma unroll
        for (int r = 0; r < 16; ++r) {
            int row = (r & 3) + 8 * (r >> 2) + 4 * lh;
            int va = svd[row], vb = svd[32 + row];
            atomicAdd(&agg[(size_t)va * HQ + n0 + lr],      logsig(a00[r]));
            atomicAdd(&agg[(size_t)va * HQ + n0 + 32 + lr], logsig(a01[r]));
            atomicAdd(&agg[(size_t)vb * HQ + n0 + lr],      logsig(a10[r]));
            atomicAdd(&agg[(size_t)vb * HQ + n0 + 32 + lr], logsig(a11[r]));
        }
    }
}

// ---------------------------------------------------------------------------
// Variable stage (MFMA): h = ls(ls(agg@W1a^T+b1a)@W2a^T); out = h@Wc^T + bc
// Block = 256 thr = 4 waves; tile = 32 variables. 50.7 KB LDS -> 3 blocks/CU.
// ---------------------------------------------------------------------------
__global__ __launch_bounds__(256) void var_mfma(
    const float* __restrict__ agg, const float* __restrict__ b1a,
    const short* __restrict__ W1ab, const short* __restrict__ W2ab,
    const float* __restrict__ Wc, const float* __restrict__ bc,
    float* __restrict__ out, int V)
{
    __shared__ short as_s[MV][HQP];     // 16896 B
    __shared__ short h1v[MV][HQP];      // 16896 B
    __shared__ float hsv[MV][DD + 4];   // 16896 B
    const int tid = threadIdx.x;
    const int v0 = blockIdx.x * MV;

    // ---- load agg tile (32 x 256 f32 = 2048 float4), convert to bf16 ----
    for (int i = tid; i < MV * 64; i += 256) {
        int v = i >> 6, q = (i & 63) << 2;
        float4 a = *(const float4*)&agg[(size_t)(v0 + v) * HQ + q];
        *(ushort4*)&as_s[v][q] = f2b4(a);
    }
    __syncthreads();

    const int wv = tid >> 6, lane = tid & 63;
    const int lr = lane & 31, lh = lane >> 5;
    const int n0 = wv * 64;

    // ---- layer 1: M=32, N=64/wave, K=256 ----
    floatx16 c0 = {}, c1 = {};
    #pragma unroll
    for (int ks = 0; ks < HQ / 16; ++ks) {
        int k = ks * 16 + lh * 8;
        bf16x8 A  = ld_bf8_lds(&as_s[lr][k]);
        bf16x8 B0 = ld_bf8_glb(&W1ab[(size_t)(n0 + lr) * HQ + k]);
        bf16x8 B1 = ld_bf8_glb(&W1ab[(size_t)(n0 + 32 + lr) * HQ + k]);
        c0 = __builtin_amdgcn_mfma_f32_32x32x16_bf16(A, B0, c0, 0, 0, 0);
        c1 = __builtin_amdgcn_mfma_f32_32x32x16_bf16(A, B1, c1, 0, 0, 0);
    }
    {
        float bn0 = b1a[n0 + lr], bn1 = b1a[n0 + 32 + lr];
        #pragma unroll
        for (int r = 0; r < 16; ++r) {
            int row = (r & 3) + 8 * (r >> 2) + 4 * lh;  // rows 0..31
            h1v[row][n0 + lr]      = (short)f2b(logsig(c0[r] + bn0));
            h1v[row][n0 + 32 + lr] = (short)f2b(logsig(c1[r] + bn1));
        }
    }
    __syncthreads();

    // ---- layer 2: M=32, N=32/wave (cols wv*32..+31), K=256 ----
    floatx16 d0 = {};
    const int n0b = wv * 32;
    #pragma unroll
    for (int ks = 0; ks < HQ / 16; ++ks) {
        int k = ks * 16 + lh * 8;
        bf16x8 A = ld_bf8_lds(&h1v[lr][k]);
        bf16x8 B = ld_bf8_glb(&W2ab[(size_t)(n0b + lr) * HQ + k]);
        d0 = __builtin_amdgcn_mfma_f32_32x32x16_bf16(A, B, d0, 0, 0, 0);
    }
    #pragma unroll
    for (int r = 0; r < 16; ++r) {
        int row = (r & 3) + 8 * (r >> 2) + 4 * lh;
        hsv[row][n0b + lr] = logsig(d0[r]);
    }
    __syncthreads();

    // ---- classifier: out[v][p] = dot(Wc[p,:], h[v,:]) + bc[p] (f32) ----
    if (tid < MV * 2) {
        int v = tid >> 1, p = tid & 1;
        const float* wrow = Wc + (size_t)p * DD;
        float acc = bc[p];
        for (int k = 0; k < DD; k += 4) {
            float4 w4 = *(const float4*)&wrow[k];
            float4 h4 = *(const float4*)&hsv[v][k];
            acc = fmaf(w4.w, h4.w, fmaf(w4.z, h4.z, fmaf(w4.y, h4.y, fmaf(w4.x, h4.x, acc))));
        }
        out[(size_t)(v0 + v) * 2 + p] = acc;
    }
}

extern "C" void kernel_launch(void* const* d_in, const int* in_sizes, int n_in,
                              void* d_out, int out_size, void* d_ws, size_t ws_size,
                              hipStream_t stream) {
    const float* vs  = (const float*)d_in[0];   // [E,128] f32
    const float* ef  = (const float*)d_in[1];   // [E,16]
    const float* sol = (const float*)d_in[2];   // [V]
    const float* W1m = (const float*)d_in[3];   // [256,145]
    const float* b1m = (const float*)d_in[4];   // [256]
    const float* W2m = (const float*)d_in[5];   // [256,256]
    const float* W1a = (const float*)d_in[6];   // [256,256]
    const float* b1a = (const float*)d_in[7];   // [256]
    const float* W2a = (const float*)d_in[8];   // [128,256]
    const float* Wc  = (const float*)d_in[9];   // [2,128]
    const float* bc  = (const float*)d_in[10];  // [2]
    const int* vidx  = (const int*)d_in[11];    // [E]
    const int* sgn   = (const int*)d_in[12];    // [E]

    const int E = in_sizes[0] / DD;   // 1,000,000 (divisible by 64)
    const int V = in_sizes[2];        //   200,000 (divisible by 32)

    char* ws = (char*)d_ws;
    size_t off = 0;
    auto alloc = [&](size_t bytes) {
        char* p = ws + off;
        off = (off + bytes + 255) & ~(size_t)255;
        return p;
    };
    // base footprint (identical to previous verified kernel): 205.2 MB
    float* agg    = (float*)alloc((size_t)V * HQ * sizeof(float));   // 204.8 MB
    short* W1mb   = (short*)alloc((size_t)256 * K1 * 2);             //  80 KB
    short* W2mb   = (short*)alloc((size_t)256 * HQ * 2);             // 128 KB
    short* W1ab   = (short*)alloc((size_t)256 * HQ * 2);             // 128 KB
    short* W2ab   = (short*)alloc((size_t)128 * HQ * 2);             //  64 KB
    // sort arrays: +5.6 MB, only used if they fit in ws
    int*   cnt    = (int*)alloc((size_t)V * sizeof(int));            // 0.8 MB
    int*   cursor = (int*)alloc((size_t)V * sizeof(int));            // 0.8 MB
    int*   perm   = (int*)alloc((size_t)E * sizeof(int));            // 4.0 MB
    const bool use_sort = (off <= ws_size);

    hipMemsetAsync(agg, 0, (size_t)V * HQ * sizeof(float), stream);
    conv_weights<<<dim3(800), dim3(256), 0, stream>>>(
        W1m, W2m, W1a, W2a, W1mb, W2mb, W1ab, W2ab);

    if (use_sort) {
        hipMemsetAsync(cnt, 0, (size_t)V * sizeof(int), stream);
        const int EG = (E + 255) / 256;
        hist_kernel<<<dim3(EG), dim3(256), 0, stream>>>(vidx, cnt, E);
        scan_kernel<<<dim3(1), dim3(SCAN_T), 0, stream>>>(cnt, cursor, V);
        scatter_kernel<<<dim3(EG), dim3(256), 0, stream>>>(vidx, cursor, perm, E);
        edge_mfma<true><<<dim3(E / ME), dim3(256), 0, stream>>>(
            vs, ef, sol, b1m, W1mb, W2mb, perm, vidx, sgn, agg, E);
    } else {
        edge_mfma<false><<<dim3(E / ME), dim3(256), 0, stream>>>(
            vs, ef, sol, b1m, W1mb, W2mb, (const int*)nullptr, vidx, sgn, agg, E);
    }
    var_mfma<<<dim3(V / MV), dim3(256), 0, stream>>>(
        agg, b1a, W1ab, W2ab, Wc, bc, (float*)d_out, V);
}

// Round 3
// 1657.432 us; speedup vs baseline: 1.3168x; 1.3168x over previous
//
#include <hip/hip_runtime.h>
#include <hip/hip_bf16.h>

typedef unsigned short u16;
typedef __attribute__((ext_vector_type(8))) short   short8;
typedef __attribute__((ext_vector_type(8))) __bf16  bf16x8;
typedef __attribute__((ext_vector_type(16))) float  floatx16;

#define DD  128   // D
#define FE  16    // edge feature dim
#define DIN 145   // D + Fe + 1
#define K1  160   // Din padded to multiple of 16
#define K1P 168   // xs LDS row stride (shorts); cols 160-167 never touched by MFMA/gather
#define HQ  256   // hidden width
#define HQP 264   // var-stage LDS row stride (shorts)
#define ME  64    // edges per block   (E = 1,000,000 is divisible by 64)
#define MV  32    // variables per block (V = 200,000 is divisible by 32)

// h1s row-XOR swizzle: row = 256 shorts = 4 x 64-short windows, row start 64-aligned,
// XOR of short-index bits 3-5 stays within the row (bijective). Bank spread: 8 distinct
// 16B-starts per 8-row group -> 4-way conflict, same as a +8 pad, but zero bytes.
#define H1IDX(r, c) ((((r) * HQ) + (c)) ^ (((r) & 7) << 3))

__device__ __forceinline__ float logsig(float x) {
    return fminf(x, 0.f) - __logf(1.f + __expf(-fabsf(x)));
}
// f32 -> bf16 RNE (bit trick; inputs are finite)
__device__ __forceinline__ u16 f2b(float f) {
    union { float f; unsigned u; } x; x.f = f;
    unsigned r = x.u + 0x7fffu + ((x.u >> 16) & 1u);
    return (u16)(r >> 16);
}
__device__ __forceinline__ ushort4 f2b4(float4 v) {
    ushort4 o; o.x = f2b(v.x); o.y = f2b(v.y); o.z = f2b(v.z); o.w = f2b(v.w);
    return o;
}
__device__ __forceinline__ bf16x8 ld_bf8_lds(const short* p) {
    return __builtin_bit_cast(bf16x8, *(const short8*)p);
}
__device__ __forceinline__ bf16x8 ld_bf8_glb(const short* p) {
    return __builtin_bit_cast(bf16x8, *(const short8*)p);
}

// ---------------------------------------------------------------------------
// Weight pre-conversion: f32 -> bf16 copies in workspace (re-done every call;
// d_ws is re-poisoned before each launch). W1m rows padded 145 -> 160 (zeros).
// ---------------------------------------------------------------------------
__global__ __launch_bounds__(256) void conv_weights(
    const float* __restrict__ W1m, const float* __restrict__ W2m,
    const float* __restrict__ W1a, const float* __restrict__ W2a,
    short* __restrict__ W1mb, short* __restrict__ W2mb,
    short* __restrict__ W1ab, short* __restrict__ W2ab)
{
    int i = blockIdx.x * 256 + threadIdx.x;
    if (i < 256 * K1) {                              // W1mb [256][160]
        int n = i / K1, k = i - n * K1;
        W1mb[i] = (k < DIN) ? (short)f2b(W1m[n * DIN + k]) : (short)0;
    } else if (i < 256 * K1 + 256 * HQ) {            // W2mb [256][256]
        int j = i - 256 * K1;
        W2mb[j] = (short)f2b(W2m[j]);
    } else if (i < 256 * K1 + 2 * 256 * HQ) {        // W1ab [256][256]
        int j = i - 256 * K1 - 256 * HQ;
        W1ab[j] = (short)f2b(W1a[j]);
    } else if (i < 256 * K1 + 2 * 256 * HQ + 128 * HQ) { // W2ab [128][256]
        int j = i - 256 * K1 - 2 * 256 * HQ;
        W2ab[j] = (short)f2b(W2a[j]);
    }
}

// ---------------------------------------------------------------------------
// Edge stage (MFMA): x = [vs|ef|sign*sol] -> ls(ls(x@W1m^T+b1m)@W2m^T)
// -> atomic segment-sum into agg[V][256] f32.
// Occupancy build: 512 thr = 8 waves (wave w owns 32 hidden cols -> 32-VGPR acc);
// LDS = xs 21504 + h1s(swizzled, unpadded) 32768 = 54272 B = 106*512
// -> 3 blocks/CU * 8 waves = 24 waves/CU = 6 waves/SIMD (__launch_bounds__(512,6)).
// svd (per-row variable id) lives in xs cols 164-165 (pad space, never aliased).
// mfma_f32_32x32x16_bf16 D layout: col=lane&31, row=(reg&3)+8*(reg>>2)+4*(lane>>5).
// ---------------------------------------------------------------------------
__global__ __launch_bounds__(512, 6) void edge_mfma(
    const float* __restrict__ vs, const float* __restrict__ ef,
    const float* __restrict__ sol, const float* __restrict__ b1m,
    const short* __restrict__ W1mb, const short* __restrict__ W2mb,
    const int* __restrict__ vidx, const int* __restrict__ esign,
    float* __restrict__ agg, int E)
{
    __shared__ short xs[ME * K1P];   // 21504 B (incl. svd ints at col 164)
    __shared__ short h1s[ME * HQ];   // 32768 B, rows XOR-swizzled via H1IDX
    const int tid = threadIdx.x;
    const int e0 = blockIdx.x * ME;

    // ---- per-row scalars: svd int + signed solution + K-pad zeros ----
    if (tid < ME) {
        int ge = e0 + tid;
        int v  = vidx[ge];
        *(int*)&xs[tid * K1P + 164] = v;                       // svd slot (pad cols)
        xs[tid * K1P + 144] = (short)f2b((float)esign[ge] * sol[v]);
        #pragma unroll
        for (int k = 145; k < K1; ++k) xs[tid * K1P + k] = 0;  // K-pad
    }
    // ---- gather: vs rows (64 x 128 f32 = 2048 float4) ----
    for (int i = tid; i < ME * 32; i += 512) {
        int e = i >> 5, q = (i & 31) << 2;
        float4 v = *(const float4*)&vs[(size_t)(e0 + e) * DD + q];
        *(ushort4*)&xs[e * K1P + q] = f2b4(v);
    }
    // ---- ef (64 x 16 f32 = 256 float4) ----
    for (int i = tid; i < ME * 4; i += 512) {
        int e = i >> 2, q = (i & 3) << 2;
        float4 v = *(const float4*)&ef[(size_t)(e0 + e) * FE + q];
        *(ushort4*)&xs[e * K1P + DD + q] = f2b4(v);
    }
    __syncthreads();

    const int wv = tid >> 6, lane = tid & 63;
    const int lr = lane & 31, lh = lane >> 5;
    const int n0 = wv * 32;                 // each of 8 waves owns 32 hidden cols

    // ---- layer 1: [64 x 160] @ [160 x 32-chunk] ----
    floatx16 a0 = {}, a1 = {};
    {
        const short* Wb = W1mb + (size_t)(n0 + lr) * K1;
        #pragma unroll 2
        for (int ks = 0; ks < K1 / 16; ++ks) {
            int k = ks * 16 + lh * 8;
            bf16x8 A0 = ld_bf8_lds(&xs[lr * K1P + k]);
            bf16x8 A1 = ld_bf8_lds(&xs[(32 + lr) * K1P + k]);
            bf16x8 B  = ld_bf8_glb(&Wb[k]);
            a0 = __builtin_amdgcn_mfma_f32_32x32x16_bf16(A0, B, a0, 0, 0, 0);
            a1 = __builtin_amdgcn_mfma_f32_32x32x16_bf16(A1, B, a1, 0, 0, 0);
        }
    }
    {
        float bn = b1m[n0 + lr];
        #pragma unroll
        for (int r = 0; r < 16; ++r) {
            int row = (r & 3) + 8 * (r >> 2) + 4 * lh;
            h1s[H1IDX(row,      n0 + lr)] = (short)f2b(logsig(a0[r] + bn));
            h1s[H1IDX(32 + row, n0 + lr)] = (short)f2b(logsig(a1[r] + bn));
        }
    }
    __syncthreads();

    // ---- layer 2: [64 x 256] @ [256 x 32-chunk] ----
    a0 = (floatx16){}; a1 = (floatx16){};
    {
        const short* Wb = W2mb + (size_t)(n0 + lr) * HQ;
        #pragma unroll 2
        for (int ks = 0; ks < HQ / 16; ++ks) {
            int k = ks * 16 + lh * 8;
            bf16x8 A0 = ld_bf8_lds(&h1s[H1IDX(lr,      k)]);
            bf16x8 A1 = ld_bf8_lds(&h1s[H1IDX(32 + lr, k)]);
            bf16x8 B  = ld_bf8_glb(&Wb[k]);
            a0 = __builtin_amdgcn_mfma_f32_32x32x16_bf16(A0, B, a0, 0, 0, 0);
            a1 = __builtin_amdgcn_mfma_f32_32x32x16_bf16(A1, B, a1, 0, 0, 0);
        }
    }
    // ---- epilogue: logsig + coalesced f32 atomics into agg ----
    #pragma unroll
    for (int r = 0; r < 16; ++r) {
        int row = (r & 3) + 8 * (r >> 2) + 4 * lh;
        int va = *(const int*)&xs[row * K1P + 164];
        int vb = *(const int*)&xs[(32 + row) * K1P + 164];
        atomicAdd(&agg[(size_t)va * HQ + n0 + lr], logsig(a0[r]));
        atomicAdd(&agg[(size_t)vb * HQ + n0 + lr], logsig(a1[r]));
    }
}

// ---------------------------------------------------------------------------
// Variable stage (MFMA): h = ls(ls(agg@W1a^T+b1a)@W2a^T); out = h@Wc^T + bc
// 512 thr = 8 waves, tile = 32 variables. LDS 50688 B = 99*512 -> 3 blocks/CU
// = 24 waves/CU = 6 waves/SIMD. Layer 1: 8 waves x 32 cols; layer 2 (128 cols):
// waves 0-3 only.
// ---------------------------------------------------------------------------
__global__ __launch_bounds__(512, 6) void var_mfma(
    const float* __restrict__ agg, const float* __restrict__ b1a,
    const short* __restrict__ W1ab, const short* __restrict__ W2ab,
    const float* __restrict__ Wc, const float* __restrict__ bc,
    float* __restrict__ out, int V)
{
    __shared__ short as_s[MV][HQP];     // 16896 B
    __shared__ short h1v[MV][HQP];      // 16896 B
    __shared__ float hsv[MV][DD + 4];   // 16896 B
    const int tid = threadIdx.x;
    const int v0 = blockIdx.x * MV;

    // ---- load agg tile (32 x 256 f32 = 2048 float4), convert to bf16 ----
    for (int i = tid; i < MV * 64; i += 512) {
        int v = i >> 6, q = (i & 63) << 2;
        float4 a = *(const float4*)&agg[(size_t)(v0 + v) * HQ + q];
        *(ushort4*)&as_s[v][q] = f2b4(a);
    }
    __syncthreads();

    const int wv = tid >> 6, lane = tid & 63;
    const int lr = lane & 31, lh = lane >> 5;
    const int n0 = wv * 32;

    // ---- layer 1: M=32, N=32/wave, K=256 ----
    floatx16 c0 = {};
    {
        const short* Wb = W1ab + (size_t)(n0 + lr) * HQ;
        #pragma unroll 2
        for (int ks = 0; ks < HQ / 16; ++ks) {
            int k = ks * 16 + lh * 8;
            bf16x8 A = ld_bf8_lds(&as_s[lr][k]);
            bf16x8 B = ld_bf8_glb(&Wb[k]);
            c0 = __builtin_amdgcn_mfma_f32_32x32x16_bf16(A, B, c0, 0, 0, 0);
        }
    }
    {
        float bn = b1a[n0 + lr];
        #pragma unroll
        for (int r = 0; r < 16; ++r) {
            int row = (r & 3) + 8 * (r >> 2) + 4 * lh;  // rows 0..31
            h1v[row][n0 + lr] = (short)f2b(logsig(c0[r] + bn));
        }
    }
    __syncthreads();

    // ---- layer 2: M=32, N=128 total -> waves 0-3, 32 cols each, K=256 ----
    if (wv < 4) {
        floatx16 d0 = {};
        const int n0b = wv * 32;
        const short* Wb = W2ab + (size_t)(n0b + lr) * HQ;
        #pragma unroll 2
        for (int ks = 0; ks < HQ / 16; ++ks) {
            int k = ks * 16 + lh * 8;
            bf16x8 A = ld_bf8_lds(&h1v[lr][k]);
            bf16x8 B = ld_bf8_glb(&Wb[k]);
            d0 = __builtin_amdgcn_mfma_f32_32x32x16_bf16(A, B, d0, 0, 0, 0);
        }
        #pragma unroll
        for (int r = 0; r < 16; ++r) {
            int row = (r & 3) + 8 * (r >> 2) + 4 * lh;
            hsv[row][n0b + lr] = logsig(d0[r]);
        }
    }
    __syncthreads();

    // ---- classifier: out[v][p] = dot(Wc[p,:], h[v,:]) + bc[p] (f32) ----
    if (tid < MV * 2) {
        int v = tid >> 1, p = tid & 1;
        const float* wrow = Wc + (size_t)p * DD;
        float acc = bc[p];
        for (int k = 0; k < DD; k += 4) {
            float4 w4 = *(const float4*)&wrow[k];
            float4 h4 = *(const float4*)&hsv[v][k];
            acc = fmaf(w4.w, h4.w, fmaf(w4.z, h4.z, fmaf(w4.y, h4.y, fmaf(w4.x, h4.x, acc))));
        }
        out[(size_t)(v0 + v) * 2 + p] = acc;
    }
}

extern "C" void kernel_launch(void* const* d_in, const int* in_sizes, int n_in,
                              void* d_out, int out_size, void* d_ws, size_t ws_size,
                              hipStream_t stream) {
    const float* vs  = (const float*)d_in[0];   // [E,128] f32
    const float* ef  = (const float*)d_in[1];   // [E,16]
    const float* sol = (const float*)d_in[2];   // [V]
    const float* W1m = (const float*)d_in[3];   // [256,145]
    const float* b1m = (const float*)d_in[4];   // [256]
    const float* W2m = (const float*)d_in[5];   // [256,256]
    const float* W1a = (const float*)d_in[6];   // [256,256]
    const float* b1a = (const float*)d_in[7];   // [256]
    const float* W2a = (const float*)d_in[8];   // [128,256]
    const float* Wc  = (const float*)d_in[9];   // [2,128]
    const float* bc  = (const float*)d_in[10];  // [2]
    const int* vidx  = (const int*)d_in[11];    // [E]
    const int* sgn   = (const int*)d_in[12];    // [E]

    const int E = in_sizes[0] / DD;   // 1,000,000 (divisible by 64)
    const int V = in_sizes[2];        //   200,000 (divisible by 32)

    char* ws = (char*)d_ws;
    float* agg = (float*)ws;                          // [V,256] f32 = 204.8 MB
    size_t off = (size_t)V * HQ * sizeof(float);
    short* W1mb = (short*)(ws + off); off += (size_t)256 * K1 * 2;  // 80 KB
    short* W2mb = (short*)(ws + off); off += (size_t)256 * HQ * 2;  // 128 KB
    short* W1ab = (short*)(ws + off); off += (size_t)256 * HQ * 2;  // 128 KB
    short* W2ab = (short*)(ws + off);                                // 64 KB

    hipMemsetAsync(agg, 0, (size_t)V * HQ * sizeof(float), stream);
    conv_weights<<<dim3(800), dim3(256), 0, stream>>>(
        W1m, W2m, W1a, W2a, W1mb, W2mb, W1ab, W2ab);
    edge_mfma<<<dim3(E / ME), dim3(512), 0, stream>>>(
        vs, ef, sol, b1m, W1mb, W2mb, vidx, sgn, agg, E);
    var_mfma<<<dim3(V / MV), dim3(512), 0, stream>>>(
        agg, b1a, W1ab, W2ab, Wc, bc, (float*)d_out, V);
}